// Round 1
// baseline (832.589 us; speedup 1.0000x reference)
//
#include <hip/hip_runtime.h>

#define NODES  30000
#define EDGES  480000
#define GRAPHS 500

// ---------------- CSR build ----------------
__global__ void count_kernel(const int* __restrict__ dst, int* __restrict__ cnt, int E) {
    int i = blockIdx.x * blockDim.x + threadIdx.x;
    if (i < E) atomicAdd(&cnt[dst[i]], 1);
}

__global__ void dinv_kernel(const int* __restrict__ cnt, float* __restrict__ dinv, int N) {
    int i = blockIdx.x * blockDim.x + threadIdx.x;
    if (i < N) dinv[i] = rsqrtf((float)cnt[i] + 1.0f);
}

// single-block exclusive scan over cnt -> rowstart (n up to 32768 handled in 4 chunks)
__global__ void scan_kernel(const int* __restrict__ cnt, int* __restrict__ rowstart, int n) {
    __shared__ int buf[1024];
    __shared__ int carry;
    if (threadIdx.x == 0) carry = 0;
    __syncthreads();
    const int PT = 8;
    for (int base = 0; base < n; base += 1024 * PT) {
        int v[PT]; int sum = 0;
        int i0 = base + (int)threadIdx.x * PT;
        #pragma unroll
        for (int j = 0; j < PT; j++) { int idx = i0 + j; int x = (idx < n) ? cnt[idx] : 0; v[j] = x; sum += x; }
        buf[threadIdx.x] = sum;
        __syncthreads();
        for (int ofs = 1; ofs < 1024; ofs <<= 1) {
            int t = (threadIdx.x >= (unsigned)ofs) ? buf[threadIdx.x - ofs] : 0;
            __syncthreads();
            buf[threadIdx.x] += t;
            __syncthreads();
        }
        int excl = buf[threadIdx.x] - sum + carry;
        #pragma unroll
        for (int j = 0; j < PT; j++) { int idx = i0 + j; if (idx < n) rowstart[idx] = excl; excl += v[j]; }
        __syncthreads();
        if (threadIdx.x == 1023) carry += buf[1023];
        __syncthreads();
    }
}

__global__ void fill_kernel(const int* __restrict__ src, const int* __restrict__ dst,
                            const int* __restrict__ rowstart, int* __restrict__ cursor,
                            int* __restrict__ csr_src, int E) {
    int i = blockIdx.x * blockDim.x + threadIdx.x;
    if (i < E) {
        int d = dst[i];
        int pos = atomicAdd(&cursor[d], 1);
        csr_src[rowstart[d] + pos] = src[i];
    }
}

// ---------------- aggregation (one block per node, dims across threads) ----------------
// out[n,:] = sum_{s in row(n)} X[s,:]*dinv[s]*dinv[n] + X[n,:]*dinv[n]^2
__global__ void agg_kernel(const float* __restrict__ X, const int* __restrict__ rowstart,
                           const int* __restrict__ cnt, const int* __restrict__ csr_src,
                           const float* __restrict__ dinv, float* __restrict__ out, int d) {
    int node = blockIdx.x;
    int t = threadIdx.x;
    if (t >= d) return;
    float di = dinv[node];
    int s = rowstart[node];
    int e = s + cnt[node];
    float acc = X[(size_t)node * d + t] * di * di;
    for (int j = s; j < e; j++) {
        int sr = csr_src[j];
        acc += X[(size_t)sr * d + t] * (dinv[sr] * di);
    }
    out[(size_t)node * d + t] = acc;
}

// ---------------- fp32 tiled GEMM: C = relu?(A[M,K] @ B[K,N] + bias) ----------------
#define BM 64
#define BN 64
#define BK 32

__global__ __launch_bounds__(256) void gemm_kernel(const float* __restrict__ A,
                                                   const float* __restrict__ B,
                                                   const float* __restrict__ bias,
                                                   float* __restrict__ C,
                                                   int M, int N, int K, int do_relu) {
    __shared__ float As[BM][BK + 1];
    __shared__ __align__(16) float Bs[BK][BN + 4];
    int t = threadIdx.x;
    int n0 = blockIdx.x * BN;
    int m0 = blockIdx.y * BM;
    int tc = t & 15;   // col group (x4)
    int tr = t >> 4;   // row within 16-row slab
    float acc[4][4] = {};
    for (int k0 = 0; k0 < K; k0 += BK) {
        #pragma unroll
        for (int i = 0; i < 8; i++) {            // A tile: 64x32
            int idx = i * 256 + t;
            int r = idx >> 5, k = idx & 31;
            int m = m0 + r, kk = k0 + k;
            As[r][k] = (m < M && kk < K) ? A[(size_t)m * K + kk] : 0.0f;
        }
        #pragma unroll
        for (int i = 0; i < 8; i++) {            // B tile: 32x64
            int idx = i * 256 + t;
            int r = idx >> 6, c = idx & 63;
            int kk = k0 + r, n = n0 + c;
            Bs[r][c] = (kk < K && n < N) ? B[(size_t)kk * N + n] : 0.0f;
        }
        __syncthreads();
        #pragma unroll
        for (int kk = 0; kk < BK; kk++) {
            float4 bv = *reinterpret_cast<const float4*>(&Bs[kk][tc * 4]);
            float a0 = As[tr][kk], a1 = As[tr + 16][kk], a2 = As[tr + 32][kk], a3 = As[tr + 48][kk];
            acc[0][0] += a0 * bv.x; acc[0][1] += a0 * bv.y; acc[0][2] += a0 * bv.z; acc[0][3] += a0 * bv.w;
            acc[1][0] += a1 * bv.x; acc[1][1] += a1 * bv.y; acc[1][2] += a1 * bv.z; acc[1][3] += a1 * bv.w;
            acc[2][0] += a2 * bv.x; acc[2][1] += a2 * bv.y; acc[2][2] += a2 * bv.z; acc[2][3] += a2 * bv.w;
            acc[3][0] += a3 * bv.x; acc[3][1] += a3 * bv.y; acc[3][2] += a3 * bv.z; acc[3][3] += a3 * bv.w;
        }
        __syncthreads();
    }
    #pragma unroll
    for (int j = 0; j < 4; j++) {
        int m = m0 + tr + 16 * j;
        if (m >= M) continue;
        #pragma unroll
        for (int i = 0; i < 4; i++) {
            int n = n0 + tc * 4 + i;
            if (n >= N) continue;
            float v = acc[j][i] + bias[n];
            if (do_relu) v = fmaxf(v, 0.0f);
            C[(size_t)m * N + n] = v;
        }
    }
}

// ---------------- segment-max pool (batch sorted) ----------------
__device__ inline int lower_bound_dev(const int* a, int n, int v) {
    int lo = 0, hi = n;
    while (lo < hi) { int mid = (lo + hi) >> 1; if (a[mid] < v) lo = mid + 1; else hi = mid; }
    return lo;
}

__global__ void pool_kernel(const float* __restrict__ H, const int* __restrict__ batch,
                            float* __restrict__ pooled, int n, int d, int G) {
    int g = blockIdx.x;
    int t = threadIdx.x;
    int s = lower_bound_dev(batch, n, g);
    int e = lower_bound_dev(batch, n, g + 1);
    if (t >= d) return;
    float m = 0.0f;   // values are post-relu (>=0); empty segment -> 0 (matches isfinite guard)
    for (int i = s; i < e; i++) m = fmaxf(m, H[(size_t)i * d + t]);
    pooled[(size_t)g * d + t] = m;
}

extern "C" void kernel_launch(void* const* d_in, const int* in_sizes, int n_in,
                              void* d_out, int out_size, void* d_ws, size_t ws_size,
                              hipStream_t stream) {
    const float* x    = (const float*)d_in[0];
    const int*   ei   = (const int*)d_in[1];
    const int*   batch= (const int*)d_in[2];
    const float* W1 = (const float*)d_in[3];  const float* b1  = (const float*)d_in[4];
    const float* W2 = (const float*)d_in[5];  const float* b2  = (const float*)d_in[6];
    const float* W3 = (const float*)d_in[7];  const float* b3  = (const float*)d_in[8];
    const float* Wf1= (const float*)d_in[9];  const float* bf1 = (const float*)d_in[10];
    const float* Wf2= (const float*)d_in[11]; const float* bf2 = (const float*)d_in[12];
    float* out = (float*)d_out;

    const int* srcp = ei;
    const int* dstp = ei + EDGES;

    char* p = (char*)d_ws;
    size_t o = 0;
    auto take = [&](size_t elems) { char* q = p + o; o += ((elems * 4 + 255) / 256) * 256; return q; };
    int*   cnt      = (int*)take(NODES);
    int*   cursor   = (int*)take(NODES);
    int*   rowstart = (int*)take(NODES);
    float* dinv     = (float*)take(NODES);
    int*   csr_src  = (int*)take(EDGES);
    float* aggbuf   = (float*)take((size_t)NODES * 156);
    float* hbuf     = (float*)take((size_t)NODES * 312);
    float* pooled   = (float*)take((size_t)GRAPHS * 312);
    float* f1       = (float*)take((size_t)GRAPHS * 1024);
    (void)ws_size;

    hipMemsetAsync(cnt, 0, NODES * sizeof(int), stream);
    hipMemsetAsync(cursor, 0, NODES * sizeof(int), stream);

    count_kernel<<<(EDGES + 255) / 256, 256, 0, stream>>>(dstp, cnt, EDGES);
    dinv_kernel<<<(NODES + 255) / 256, 256, 0, stream>>>(cnt, dinv, NODES);
    scan_kernel<<<1, 1024, 0, stream>>>(cnt, rowstart, NODES);
    fill_kernel<<<(EDGES + 255) / 256, 256, 0, stream>>>(srcp, dstp, rowstart, cursor, csr_src, EDGES);

    dim3 blk(256);

    // layer 1: agg(x) [N,78] -> @W1 + b1, relu -> hbuf [N,78]
    agg_kernel<<<NODES, 128, 0, stream>>>(x, rowstart, cnt, csr_src, dinv, aggbuf, 78);
    gemm_kernel<<<dim3((78 + BN - 1) / BN, (NODES + BM - 1) / BM), blk, 0, stream>>>(
        aggbuf, W1, b1, hbuf, NODES, 78, 78, 1);

    // layer 2: agg(h1) [N,78] -> @W2 + b2, relu -> hbuf [N,156]
    agg_kernel<<<NODES, 128, 0, stream>>>(hbuf, rowstart, cnt, csr_src, dinv, aggbuf, 78);
    gemm_kernel<<<dim3((156 + BN - 1) / BN, (NODES + BM - 1) / BM), blk, 0, stream>>>(
        aggbuf, W2, b2, hbuf, NODES, 156, 78, 1);

    // layer 3: agg(h2) [N,156] -> @W3 + b3, relu -> hbuf [N,312]
    agg_kernel<<<NODES, 192, 0, stream>>>(hbuf, rowstart, cnt, csr_src, dinv, aggbuf, 156);
    gemm_kernel<<<dim3((312 + BN - 1) / BN, (NODES + BM - 1) / BM), blk, 0, stream>>>(
        aggbuf, W3, b3, hbuf, NODES, 312, 156, 1);

    // pool -> [G,312]
    pool_kernel<<<GRAPHS, 320, 0, stream>>>(hbuf, batch, pooled, NODES, 312, GRAPHS);

    // fc1: [G,312]@[312,1024]+bf1, relu
    gemm_kernel<<<dim3((1024 + BN - 1) / BN, (GRAPHS + BM - 1) / BM), blk, 0, stream>>>(
        pooled, Wf1, bf1, f1, GRAPHS, 1024, 312, 1);

    // fc2: [G,1024]@[1024,128]+bf2 -> out
    gemm_kernel<<<dim3((128 + BN - 1) / BN, (GRAPHS + BM - 1) / BM), blk, 0, stream>>>(
        f1, Wf2, bf2, out, GRAPHS, 128, 1024, 0);
}

// Round 2
// 622.496 us; speedup vs baseline: 1.3375x; 1.3375x over previous
//
#include <hip/hip_runtime.h>

#define NODES  30000
#define EDGES  480000
#define GRAPHS 500

// ---------------- CSR build ----------------
__global__ void count_kernel(const int* __restrict__ dst, int* __restrict__ cnt, int E) {
    int i = blockIdx.x * blockDim.x + threadIdx.x;
    if (i < E) atomicAdd(&cnt[dst[i]], 1);
}

__global__ void dinv_kernel(const int* __restrict__ cnt, float* __restrict__ dinv, int N) {
    int i = blockIdx.x * blockDim.x + threadIdx.x;
    if (i < N) dinv[i] = rsqrtf((float)cnt[i] + 1.0f);
}

// single-block exclusive scan over cnt -> rowstart
__global__ void scan_kernel(const int* __restrict__ cnt, int* __restrict__ rowstart, int n) {
    __shared__ int buf[1024];
    __shared__ int carry;
    if (threadIdx.x == 0) carry = 0;
    __syncthreads();
    const int PT = 8;
    for (int base = 0; base < n; base += 1024 * PT) {
        int v[PT]; int sum = 0;
        int i0 = base + (int)threadIdx.x * PT;
        #pragma unroll
        for (int j = 0; j < PT; j++) { int idx = i0 + j; int x = (idx < n) ? cnt[idx] : 0; v[j] = x; sum += x; }
        buf[threadIdx.x] = sum;
        __syncthreads();
        for (int ofs = 1; ofs < 1024; ofs <<= 1) {
            int t = (threadIdx.x >= (unsigned)ofs) ? buf[threadIdx.x - ofs] : 0;
            __syncthreads();
            buf[threadIdx.x] += t;
            __syncthreads();
        }
        int excl = buf[threadIdx.x] - sum + carry;
        #pragma unroll
        for (int j = 0; j < PT; j++) { int idx = i0 + j; if (idx < n) rowstart[idx] = excl; excl += v[j]; }
        __syncthreads();
        if (threadIdx.x == 1023) carry += buf[1023];
        __syncthreads();
    }
}

__global__ void fill_kernel(const int* __restrict__ src, const int* __restrict__ dst,
                            const int* __restrict__ rowstart, int* __restrict__ cursor,
                            int* __restrict__ csr_src, int E) {
    int i = blockIdx.x * blockDim.x + threadIdx.x;
    if (i < E) {
        int d = dst[i];
        int pos = atomicAdd(&cursor[d], 1);
        csr_src[rowstart[d] + pos] = src[i];
    }
}

// ---------------- aggregation (one block per node, dims across threads) ----------------
__global__ void agg_kernel(const float* __restrict__ X, const int* __restrict__ rowstart,
                           const int* __restrict__ cnt, const int* __restrict__ csr_src,
                           const float* __restrict__ dinv, float* __restrict__ out, int d) {
    int node = blockIdx.x;
    int t = threadIdx.x;
    if (t >= d) return;
    float di = dinv[node];
    int s = rowstart[node];
    int e = s + cnt[node];
    float acc = X[(size_t)node * d + t] * di * di;
    for (int j = s; j < e; j++) {
        int sr = csr_src[j];
        acc += X[(size_t)sr * d + t] * (dinv[sr] * di);
    }
    out[(size_t)node * d + t] = acc;
}

// ---------------- fp32 tiled GEMM: C = relu?(A[M,K] @ B[K,N] + bias) ----------------
#define BM 64
#define BN 64
#define BK 32

__global__ __launch_bounds__(256) void gemm_kernel(const float* __restrict__ A,
                                                   const float* __restrict__ B,
                                                   const float* __restrict__ bias,
                                                   float* __restrict__ C,
                                                   int M, int N, int K, int do_relu) {
    __shared__ float As[BM][BK + 1];
    __shared__ __align__(16) float Bs[BK][BN + 4];
    int t = threadIdx.x;
    int n0 = blockIdx.x * BN;
    int m0 = blockIdx.y * BM;
    int tc = t & 15;
    int tr = t >> 4;
    float acc[4][4] = {};
    for (int k0 = 0; k0 < K; k0 += BK) {
        #pragma unroll
        for (int i = 0; i < 8; i++) {
            int idx = i * 256 + t;
            int r = idx >> 5, k = idx & 31;
            int m = m0 + r, kk = k0 + k;
            As[r][k] = (m < M && kk < K) ? A[(size_t)m * K + kk] : 0.0f;
        }
        #pragma unroll
        for (int i = 0; i < 8; i++) {
            int idx = i * 256 + t;
            int r = idx >> 6, c = idx & 63;
            int kk = k0 + r, n = n0 + c;
            Bs[r][c] = (kk < K && n < N) ? B[(size_t)kk * N + n] : 0.0f;
        }
        __syncthreads();
        #pragma unroll
        for (int kk = 0; kk < BK; kk++) {
            float4 bv = *reinterpret_cast<const float4*>(&Bs[kk][tc * 4]);
            float a0 = As[tr][kk], a1 = As[tr + 16][kk], a2 = As[tr + 32][kk], a3 = As[tr + 48][kk];
            acc[0][0] += a0 * bv.x; acc[0][1] += a0 * bv.y; acc[0][2] += a0 * bv.z; acc[0][3] += a0 * bv.w;
            acc[1][0] += a1 * bv.x; acc[1][1] += a1 * bv.y; acc[1][2] += a1 * bv.z; acc[1][3] += a1 * bv.w;
            acc[2][0] += a2 * bv.x; acc[2][1] += a2 * bv.y; acc[2][2] += a2 * bv.z; acc[2][3] += a2 * bv.w;
            acc[3][0] += a3 * bv.x; acc[3][1] += a3 * bv.y; acc[3][2] += a3 * bv.z; acc[3][3] += a3 * bv.w;
        }
        __syncthreads();
    }
    #pragma unroll
    for (int j = 0; j < 4; j++) {
        int m = m0 + tr + 16 * j;
        if (m >= M) continue;
        #pragma unroll
        for (int i = 0; i < 4; i++) {
            int n = n0 + tc * 4 + i;
            if (n >= N) continue;
            float v = acc[j][i] + bias[n];
            if (do_relu) v = fmaxf(v, 0.0f);
            C[(size_t)m * N + n] = v;
        }
    }
}

// ---------------- segment-max pool (batch sorted) ----------------
__device__ inline int lower_bound_dev(const int* a, int n, int v) {
    int lo = 0, hi = n;
    while (lo < hi) { int mid = (lo + hi) >> 1; if (a[mid] < v) lo = mid + 1; else hi = mid; }
    return lo;
}

__global__ void pool_kernel(const float* __restrict__ H, const int* __restrict__ batch,
                            float* __restrict__ pooled, int n, int d, int G) {
    int g = blockIdx.x;
    int t = threadIdx.x;
    int s = lower_bound_dev(batch, n, g);
    int e = lower_bound_dev(batch, n, g + 1);
    if (t >= d) return;
    float m = 0.0f;   // post-relu values >= 0; empty segment -> 0 matches isfinite guard
    for (int i = s; i < e; i++) m = fmaxf(m, H[(size_t)i * d + t]);
    pooled[(size_t)g * d + t] = m;
}

// ---------------- fused FC: out[g,:] = relu(pooled[g,:]@Wf1+bf1)@Wf2 + bf2 ----------------
// one block (256 threads) per graph; f1 row (1024) staged in LDS
__global__ __launch_bounds__(256) void fc_fused_kernel(const float* __restrict__ pooled,
                                                       const float* __restrict__ Wf1,
                                                       const float* __restrict__ bf1,
                                                       const float* __restrict__ Wf2,
                                                       const float* __restrict__ bf2,
                                                       float* __restrict__ out) {
    __shared__ float pl[312];
    __shared__ float f1[1024];
    __shared__ float part[256];
    int g = blockIdx.x;
    int t = threadIdx.x;
    for (int i = t; i < 312; i += 256) pl[i] = pooled[(size_t)g * 312 + i];
    __syncthreads();

    // f1[j] = relu(sum_k pl[k] * Wf1[k*1024 + j] + bf1[j]); each thread does 4 j's
    float acc0 = 0.f, acc1 = 0.f, acc2 = 0.f, acc3 = 0.f;
    for (int k = 0; k < 312; k++) {
        float pk = pl[k];
        const float* w = Wf1 + (size_t)k * 1024 + t;
        acc0 += pk * w[0];
        acc1 += pk * w[256];
        acc2 += pk * w[512];
        acc3 += pk * w[768];
    }
    f1[t]       = fmaxf(acc0 + bf1[t], 0.f);
    f1[t + 256] = fmaxf(acc1 + bf1[t + 256], 0.f);
    f1[t + 512] = fmaxf(acc2 + bf1[t + 512], 0.f);
    f1[t + 768] = fmaxf(acc3 + bf1[t + 768], 0.f);
    __syncthreads();

    // out[n] = sum_k f1[k] * Wf2[k*128 + n] + bf2[n]; n = t&127, k-half = t>>7
    int n = t & 127;
    int h = t >> 7;
    float p = 0.f;
    const float* w2 = Wf2 + (size_t)h * 512 * 128 + n;
    const float* fl = f1 + h * 512;
    for (int k = 0; k < 512; k++) p += fl[k] * w2[(size_t)k * 128];
    part[t] = p;
    __syncthreads();
    if (t < 128) out[(size_t)g * 128 + t] = part[t] + part[t + 128] + bf2[t];
}

extern "C" void kernel_launch(void* const* d_in, const int* in_sizes, int n_in,
                              void* d_out, int out_size, void* d_ws, size_t ws_size,
                              hipStream_t stream) {
    const float* x    = (const float*)d_in[0];
    const int*   ei   = (const int*)d_in[1];
    const int*   batch= (const int*)d_in[2];
    const float* W1 = (const float*)d_in[3];  const float* b1  = (const float*)d_in[4];
    const float* W2 = (const float*)d_in[5];  const float* b2  = (const float*)d_in[6];
    const float* W3 = (const float*)d_in[7];  const float* b3  = (const float*)d_in[8];
    const float* Wf1= (const float*)d_in[9];  const float* bf1 = (const float*)d_in[10];
    const float* Wf2= (const float*)d_in[11]; const float* bf2 = (const float*)d_in[12];
    float* out = (float*)d_out;

    const int* srcp = ei;
    const int* dstp = ei + EDGES;

    char* p = (char*)d_ws;
    size_t o = 0;
    auto take = [&](size_t elems) { char* q = p + o; o += ((elems * 4 + 255) / 256) * 256; return q; };
    int*   cnt      = (int*)take(NODES);
    int*   cursor   = (int*)take(NODES);
    int*   rowstart = (int*)take(NODES);
    float* dinv     = (float*)take(NODES);
    int*   csr_src  = (int*)take(EDGES);
    float* aggbuf   = (float*)take((size_t)NODES * 156);
    float* hbuf     = (float*)take((size_t)NODES * 312);
    float* pooled   = (float*)take((size_t)GRAPHS * 312);
    (void)ws_size;

    hipMemsetAsync(cnt, 0, NODES * sizeof(int), stream);
    hipMemsetAsync(cursor, 0, NODES * sizeof(int), stream);

    count_kernel<<<(EDGES + 255) / 256, 256, 0, stream>>>(dstp, cnt, EDGES);
    dinv_kernel<<<(NODES + 255) / 256, 256, 0, stream>>>(cnt, dinv, NODES);
    scan_kernel<<<1, 1024, 0, stream>>>(cnt, rowstart, NODES);
    fill_kernel<<<(EDGES + 255) / 256, 256, 0, stream>>>(srcp, dstp, rowstart, cursor, csr_src, EDGES);

    dim3 blk(256);

    // layer 1
    agg_kernel<<<NODES, 128, 0, stream>>>(x, rowstart, cnt, csr_src, dinv, aggbuf, 78);
    gemm_kernel<<<dim3(2, (NODES + BM - 1) / BM), blk, 0, stream>>>(
        aggbuf, W1, b1, hbuf, NODES, 78, 78, 1);

    // layer 2
    agg_kernel<<<NODES, 128, 0, stream>>>(hbuf, rowstart, cnt, csr_src, dinv, aggbuf, 78);
    gemm_kernel<<<dim3(3, (NODES + BM - 1) / BM), blk, 0, stream>>>(
        aggbuf, W2, b2, hbuf, NODES, 156, 78, 1);

    // layer 3
    agg_kernel<<<NODES, 192, 0, stream>>>(hbuf, rowstart, cnt, csr_src, dinv, aggbuf, 156);
    gemm_kernel<<<dim3(5, (NODES + BM - 1) / BM), blk, 0, stream>>>(
        aggbuf, W3, b3, hbuf, NODES, 312, 156, 1);

    // pool -> [G,312]
    pool_kernel<<<GRAPHS, 320, 0, stream>>>(hbuf, batch, pooled, NODES, 312, GRAPHS);

    // fused FC1+FC2 -> out
    fc_fused_kernel<<<GRAPHS, 256, 0, stream>>>(pooled, Wf1, bf1, Wf2, bf2, out);
}

// Round 3
// 511.684 us; speedup vs baseline: 1.6272x; 1.2166x over previous
//
#include <hip/hip_runtime.h>

#define NODES  30000
#define EDGES  480000
#define GRAPHS 500
#define MPAD   30016   // 64*469

typedef __bf16 bf16x8 __attribute__((ext_vector_type(8)));
typedef float  f32x4  __attribute__((ext_vector_type(4)));

// ---------------- fp32 -> bf16 hi/lo split (RNE both halves) ----------------
__device__ __forceinline__ void split_f32(float a, unsigned short& hi, unsigned short& lo) {
    unsigned int u = __float_as_uint(a);
    unsigned int rh = (u + 0x7fffu + ((u >> 16) & 1u)) & 0xffff0000u;
    hi = (unsigned short)(rh >> 16);
    float l = a - __uint_as_float(rh);      // exact (Sterbenz-style)
    unsigned int ul = __float_as_uint(l);
    lo = (unsigned short)((ul + 0x7fffu + ((ul >> 16) & 1u)) >> 16);
}

__device__ __forceinline__ void gload_lds16(const void* g, void* l) {
    __builtin_amdgcn_global_load_lds(
        (__attribute__((address_space(1))) void*)g,
        (__attribute__((address_space(3))) void*)l, 16, 0, 0);
}

// ---------------- CSR build ----------------
__global__ void count_kernel(const int* __restrict__ dst, int* __restrict__ cnt, int E) {
    int i = blockIdx.x * blockDim.x + threadIdx.x;
    if (i < E) atomicAdd(&cnt[dst[i]], 1);
}

__global__ void dinv_kernel(const int* __restrict__ cnt, float* __restrict__ dinv, int N) {
    int i = blockIdx.x * blockDim.x + threadIdx.x;
    if (i < N) dinv[i] = rsqrtf((float)cnt[i] + 1.0f);
}

__global__ void scan_kernel(const int* __restrict__ cnt, int* __restrict__ rowstart, int n) {
    __shared__ int buf[1024];
    __shared__ int carry;
    if (threadIdx.x == 0) carry = 0;
    __syncthreads();
    const int PT = 8;
    for (int base = 0; base < n; base += 1024 * PT) {
        int v[PT]; int sum = 0;
        int i0 = base + (int)threadIdx.x * PT;
        #pragma unroll
        for (int j = 0; j < PT; j++) { int idx = i0 + j; int x = (idx < n) ? cnt[idx] : 0; v[j] = x; sum += x; }
        buf[threadIdx.x] = sum;
        __syncthreads();
        for (int ofs = 1; ofs < 1024; ofs <<= 1) {
            int t = (threadIdx.x >= (unsigned)ofs) ? buf[threadIdx.x - ofs] : 0;
            __syncthreads();
            buf[threadIdx.x] += t;
            __syncthreads();
        }
        int excl = buf[threadIdx.x] - sum + carry;
        #pragma unroll
        for (int j = 0; j < PT; j++) { int idx = i0 + j; if (idx < n) rowstart[idx] = excl; excl += v[j]; }
        __syncthreads();
        if (threadIdx.x == 1023) carry += buf[1023];
        __syncthreads();
    }
}

__global__ void fill_kernel(const int* __restrict__ src, const int* __restrict__ dst,
                            const int* __restrict__ rowstart, int* __restrict__ cursor,
                            int* __restrict__ csr_src, int E) {
    int i = blockIdx.x * blockDim.x + threadIdx.x;
    if (i < E) {
        int d = dst[i];
        int pos = atomicAdd(&cursor[d], 1);
        csr_src[rowstart[d] + pos] = src[i];
    }
}

// ---------------- weight split+transpose: W[K,N] fp32 -> Wt_hi/lo[Nalloc][Kp] bf16 ----------------
__global__ void wsplit_kernel(const float* __restrict__ W, unsigned short* __restrict__ hi,
                              unsigned short* __restrict__ lo, int K, int N, int Kp) {
    int n = blockIdx.x, k = threadIdx.x;     // blockDim.x == Kp, gridDim.x == Nalloc
    float v = (n < N && k < K) ? W[(size_t)k * N + n] : 0.0f;
    unsigned short h, l;
    split_f32(v, h, l);
    hi[(size_t)n * Kp + k] = h;
    lo[(size_t)n * Kp + k] = l;
}

// ---------------- aggregation -> hi/lo bf16 planes, zero-padded to Kp ----------------
__global__ void agg_split_kernel(const float* __restrict__ X, const int* __restrict__ rowstart,
                                 const int* __restrict__ cnt, const int* __restrict__ csr_src,
                                 const float* __restrict__ dinv, unsigned short* __restrict__ ohi,
                                 unsigned short* __restrict__ olo, int d, int Kp) {
    int node = blockIdx.x;
    int t = threadIdx.x;
    if (t >= Kp) return;
    float acc = 0.0f;
    if (t < d) {
        float di = dinv[node];
        int s = rowstart[node];
        int e = s + cnt[node];
        acc = X[(size_t)node * d + t] * di * di;
        for (int j = s; j < e; j++) {
            int sr = csr_src[j];
            acc += X[(size_t)sr * d + t] * (dinv[sr] * di);
        }
    }
    unsigned short h, l;
    split_f32(acc, h, l);
    ohi[(size_t)node * Kp + t] = h;
    olo[(size_t)node * Kp + t] = l;
}

// ---------------- split-bf16 MFMA GEMM: C[M,N] = relu?(A @ B + bias) ----------------
// A given as hi/lo bf16 [MPAD][Kp]; B given transposed as hi/lo bf16 [Nalloc][Kp].
// Block: 256 thr (4 waves), tile 64x64. Wave w -> 32x32 subtile (wm=w&1, wn=w>>1).
// LDS layout per array: [q(4)][row(64)][8 bf16] staged by global_load_lds width 16.
__global__ __launch_bounds__(256) void mfma_gemm_kernel(
    const unsigned short* __restrict__ Ahi, const unsigned short* __restrict__ Alo,
    const unsigned short* __restrict__ Bhi, const unsigned short* __restrict__ Blo,
    const float* __restrict__ bias, float* __restrict__ C,
    int M, int N, int Kp, int nChunks, int do_relu)
{
    __shared__ __align__(16) unsigned short lds[4][4][64][8];   // 16 KB
    int t = threadIdx.x;
    int wv = t >> 6, ln = t & 63;
    int m0 = blockIdx.y * 64, n0 = blockIdx.x * 64;
    int q = ln >> 4, l16 = ln & 15;
    int wm = wv & 1, wn = wv >> 1;

    const unsigned short* garr = (wv == 0) ? Ahi : (wv == 1) ? Alo : (wv == 2) ? Bhi : Blo;
    int row0 = ((wv < 2) ? m0 : n0) + ln;

    f32x4 acc[2][2] = {};

    for (int ck = 0; ck < nChunks; ck++) {
        const unsigned short* g = garr + (size_t)row0 * Kp + ck * 32;
        #pragma unroll
        for (int qq = 0; qq < 4; qq++)
            gload_lds16(g + qq * 8, &lds[wv][qq][0][0]);
        __syncthreads();   // drains vmcnt (DMA) before reads

        bf16x8 ah[2], al[2], bh[2], bl[2];
        #pragma unroll
        for (int i = 0; i < 2; i++) {
            int ra = wm * 32 + i * 16 + l16;
            int rb = wn * 32 + i * 16 + l16;
            ah[i] = *(const bf16x8*)&lds[0][q][ra][0];
            al[i] = *(const bf16x8*)&lds[1][q][ra][0];
            bh[i] = *(const bf16x8*)&lds[2][q][rb][0];
            bl[i] = *(const bf16x8*)&lds[3][q][rb][0];
        }
        #pragma unroll
        for (int i = 0; i < 2; i++)
            #pragma unroll
            for (int j = 0; j < 2; j++) {
                acc[i][j] = __builtin_amdgcn_mfma_f32_16x16x32_bf16(ah[i], bh[j], acc[i][j], 0, 0, 0);
                acc[i][j] = __builtin_amdgcn_mfma_f32_16x16x32_bf16(ah[i], bl[j], acc[i][j], 0, 0, 0);
                acc[i][j] = __builtin_amdgcn_mfma_f32_16x16x32_bf16(al[i], bh[j], acc[i][j], 0, 0, 0);
            }
        __syncthreads();   // protect LDS before restaging
    }

    // epilogue: C/D layout col=lane&15, row=(lane>>4)*4+reg
    #pragma unroll
    for (int i = 0; i < 2; i++) {
        int rbase = m0 + wm * 32 + i * 16 + q * 4;
        #pragma unroll
        for (int j = 0; j < 2; j++) {
            int col = n0 + wn * 32 + j * 16 + l16;
            if (col >= N) continue;
            float bv = bias[col];
            #pragma unroll
            for (int r = 0; r < 4; r++) {
                int row = rbase + r;
                if (row < M) {
                    float v = acc[i][j][r] + bv;
                    if (do_relu) v = fmaxf(v, 0.0f);
                    C[(size_t)row * N + col] = v;
                }
            }
        }
    }
}

// ---------------- segment-max pool (batch sorted) ----------------
__device__ inline int lower_bound_dev(const int* a, int n, int v) {
    int lo = 0, hi = n;
    while (lo < hi) { int mid = (lo + hi) >> 1; if (a[mid] < v) lo = mid + 1; else hi = mid; }
    return lo;
}

__global__ void pool_kernel(const float* __restrict__ H, const int* __restrict__ batch,
                            float* __restrict__ pooled, int n, int d, int G) {
    int g = blockIdx.x;
    int t = threadIdx.x;
    int s = lower_bound_dev(batch, n, g);
    int e = lower_bound_dev(batch, n, g + 1);
    if (t >= d) return;
    float m = 0.0f;
    for (int i = s; i < e; i++) m = fmaxf(m, H[(size_t)i * d + t]);
    pooled[(size_t)g * d + t] = m;
}

// ---------------- fused FC: out[g,:] = relu(pooled[g,:]@Wf1+bf1)@Wf2 + bf2 ----------------
__global__ __launch_bounds__(256) void fc_fused_kernel(const float* __restrict__ pooled,
                                                       const float* __restrict__ Wf1,
                                                       const float* __restrict__ bf1,
                                                       const float* __restrict__ Wf2,
                                                       const float* __restrict__ bf2,
                                                       float* __restrict__ out) {
    __shared__ float pl[312];
    __shared__ float f1[1024];
    __shared__ float part[256];
    int g = blockIdx.x;
    int t = threadIdx.x;
    for (int i = t; i < 312; i += 256) pl[i] = pooled[(size_t)g * 312 + i];
    __syncthreads();

    float acc0 = 0.f, acc1 = 0.f, acc2 = 0.f, acc3 = 0.f;
    for (int k = 0; k < 312; k++) {
        float pk = pl[k];
        const float* w = Wf1 + (size_t)k * 1024 + t;
        acc0 += pk * w[0];
        acc1 += pk * w[256];
        acc2 += pk * w[512];
        acc3 += pk * w[768];
    }
    f1[t]       = fmaxf(acc0 + bf1[t], 0.f);
    f1[t + 256] = fmaxf(acc1 + bf1[t + 256], 0.f);
    f1[t + 512] = fmaxf(acc2 + bf1[t + 512], 0.f);
    f1[t + 768] = fmaxf(acc3 + bf1[t + 768], 0.f);
    __syncthreads();

    int n = t & 127;
    int h = t >> 7;
    float p = 0.f;
    const float* w2 = Wf2 + (size_t)h * 512 * 128 + n;
    const float* fl = f1 + h * 512;
    for (int k = 0; k < 512; k++) p += fl[k] * w2[(size_t)k * 128];
    part[t] = p;
    __syncthreads();
    if (t < 128) out[(size_t)g * 128 + t] = part[t] + part[t + 128] + bf2[t];
}

extern "C" void kernel_launch(void* const* d_in, const int* in_sizes, int n_in,
                              void* d_out, int out_size, void* d_ws, size_t ws_size,
                              hipStream_t stream) {
    const float* x    = (const float*)d_in[0];
    const int*   ei   = (const int*)d_in[1];
    const int*   batch= (const int*)d_in[2];
    const float* W1 = (const float*)d_in[3];  const float* b1  = (const float*)d_in[4];
    const float* W2 = (const float*)d_in[5];  const float* b2  = (const float*)d_in[6];
    const float* W3 = (const float*)d_in[7];  const float* b3  = (const float*)d_in[8];
    const float* Wf1= (const float*)d_in[9];  const float* bf1 = (const float*)d_in[10];
    const float* Wf2= (const float*)d_in[11]; const float* bf2 = (const float*)d_in[12];
    float* out = (float*)d_out;

    const int* srcp = ei;
    const int* dstp = ei + EDGES;

    char* p = (char*)d_ws;
    size_t o = 0;
    auto takeB = [&](size_t bytes) { char* q = p + o; o += (bytes + 255) & ~(size_t)255; return q; };
    int*   cnt      = (int*)takeB(NODES * 4);
    int*   cursor   = (int*)takeB(NODES * 4);
    int*   rowstart = (int*)takeB(NODES * 4);
    float* dinv     = (float*)takeB(NODES * 4);
    int*   csr_src  = (int*)takeB(EDGES * 4);
    unsigned short* aggH = (unsigned short*)takeB((size_t)MPAD * 160 * 2);
    unsigned short* aggL = (unsigned short*)takeB((size_t)MPAD * 160 * 2);
    float* hbuf   = (float*)takeB((size_t)NODES * 312 * 4);
    float* pooled = (float*)takeB((size_t)GRAPHS * 312 * 4);
    unsigned short* Wt1h = (unsigned short*)takeB(128 * 96 * 2);
    unsigned short* Wt1l = (unsigned short*)takeB(128 * 96 * 2);
    unsigned short* Wt2h = (unsigned short*)takeB(192 * 96 * 2);
    unsigned short* Wt2l = (unsigned short*)takeB(192 * 96 * 2);
    unsigned short* Wt3h = (unsigned short*)takeB(320 * 160 * 2);
    unsigned short* Wt3l = (unsigned short*)takeB(320 * 160 * 2);
    (void)ws_size;

    hipMemsetAsync(cnt, 0, NODES * sizeof(int), stream);
    hipMemsetAsync(cursor, 0, NODES * sizeof(int), stream);

    // weight split/transpose (tiny)
    wsplit_kernel<<<128, 96, 0, stream>>>(W1, Wt1h, Wt1l, 78, 78, 96);
    wsplit_kernel<<<192, 96, 0, stream>>>(W2, Wt2h, Wt2l, 78, 156, 96);
    wsplit_kernel<<<320, 160, 0, stream>>>(W3, Wt3h, Wt3l, 156, 312, 160);

    // CSR build
    count_kernel<<<(EDGES + 255) / 256, 256, 0, stream>>>(dstp, cnt, EDGES);
    dinv_kernel<<<(NODES + 255) / 256, 256, 0, stream>>>(cnt, dinv, NODES);
    scan_kernel<<<1, 1024, 0, stream>>>(cnt, rowstart, NODES);
    fill_kernel<<<(EDGES + 255) / 256, 256, 0, stream>>>(srcp, dstp, rowstart, cursor, csr_src, EDGES);

    // layer 1: agg(x)[N,78] -> split; MFMA gemm -> hbuf[N,78]
    agg_split_kernel<<<NODES, 128, 0, stream>>>(x, rowstart, cnt, csr_src, dinv, aggH, aggL, 78, 96);
    mfma_gemm_kernel<<<dim3(2, MPAD / 64), 256, 0, stream>>>(aggH, aggL, Wt1h, Wt1l, b1, hbuf,
                                                             NODES, 78, 96, 3, 1);
    // layer 2
    agg_split_kernel<<<NODES, 128, 0, stream>>>(hbuf, rowstart, cnt, csr_src, dinv, aggH, aggL, 78, 96);
    mfma_gemm_kernel<<<dim3(3, MPAD / 64), 256, 0, stream>>>(aggH, aggL, Wt2h, Wt2l, b2, hbuf,
                                                             NODES, 156, 96, 3, 1);
    // layer 3
    agg_split_kernel<<<NODES, 192, 0, stream>>>(hbuf, rowstart, cnt, csr_src, dinv, aggH, aggL, 156, 160);
    mfma_gemm_kernel<<<dim3(5, MPAD / 64), 256, 0, stream>>>(aggH, aggL, Wt3h, Wt3l, b3, hbuf,
                                                             NODES, 312, 160, 5, 1);

    // pool -> [G,312]
    pool_kernel<<<GRAPHS, 320, 0, stream>>>(hbuf, batch, pooled, NODES, 312, GRAPHS);

    // fused FC1+FC2 -> out
    fc_fused_kernel<<<GRAPHS, 256, 0, stream>>>(pooled, Wf1, bf1, Wf2, bf2, out);
}

// Round 4
// 430.708 us; speedup vs baseline: 1.9331x; 1.1880x over previous
//
#include <hip/hip_runtime.h>

#define NODES  30000
#define EDGES  480000
#define GRAPHS 500
#define MPAD   30016   // 64*469

typedef __bf16 bf16x8 __attribute__((ext_vector_type(8)));
typedef float  f32x4  __attribute__((ext_vector_type(4)));

// ---------------- fp32 -> bf16 hi/lo split (RNE both halves) ----------------
__device__ __forceinline__ void split_f32(float a, unsigned short& hi, unsigned short& lo) {
    unsigned int u = __float_as_uint(a);
    unsigned int rh = (u + 0x7fffu + ((u >> 16) & 1u)) & 0xffff0000u;
    hi = (unsigned short)(rh >> 16);
    float l = a - __uint_as_float(rh);
    unsigned int ul = __float_as_uint(l);
    lo = (unsigned short)((ul + 0x7fffu + ((ul >> 16) & 1u)) >> 16);
}

__device__ __forceinline__ void gload_lds16(const void* g, void* l) {
    __builtin_amdgcn_global_load_lds(
        (__attribute__((address_space(1))) void*)g,
        (__attribute__((address_space(3))) void*)l, 16, 0, 0);
}

// ---------------- CSR build ----------------
__global__ void count_kernel(const int* __restrict__ dst, int* __restrict__ cnt, int E) {
    int i = blockIdx.x * blockDim.x + threadIdx.x;
    if (i < E) atomicAdd(&cnt[dst[i]], 1);
}

__global__ void dinv_kernel(const int* __restrict__ cnt, float* __restrict__ dinv, int N) {
    int i = blockIdx.x * blockDim.x + threadIdx.x;
    if (i < N) dinv[i] = rsqrtf((float)cnt[i] + 1.0f);
}

__global__ void scan_kernel(const int* __restrict__ cnt, int* __restrict__ rowstart, int n) {
    __shared__ int buf[1024];
    __shared__ int carry;
    if (threadIdx.x == 0) carry = 0;
    __syncthreads();
    const int PT = 8;
    for (int base = 0; base < n; base += 1024 * PT) {
        int v[PT]; int sum = 0;
        int i0 = base + (int)threadIdx.x * PT;
        #pragma unroll
        for (int j = 0; j < PT; j++) { int idx = i0 + j; int x = (idx < n) ? cnt[idx] : 0; v[j] = x; sum += x; }
        buf[threadIdx.x] = sum;
        __syncthreads();
        for (int ofs = 1; ofs < 1024; ofs <<= 1) {
            int t = (threadIdx.x >= (unsigned)ofs) ? buf[threadIdx.x - ofs] : 0;
            __syncthreads();
            buf[threadIdx.x] += t;
            __syncthreads();
        }
        int excl = buf[threadIdx.x] - sum + carry;
        #pragma unroll
        for (int j = 0; j < PT; j++) { int idx = i0 + j; if (idx < n) rowstart[idx] = excl; excl += v[j]; }
        __syncthreads();
        if (threadIdx.x == 1023) carry += buf[1023];
        __syncthreads();
    }
}

__global__ void fill_kernel(const int* __restrict__ src, const int* __restrict__ dst,
                            const int* __restrict__ rowstart, int* __restrict__ cursor,
                            int* __restrict__ csr_src, int E) {
    int i = blockIdx.x * blockDim.x + threadIdx.x;
    if (i < E) {
        int d = dst[i];
        int pos = atomicAdd(&cursor[d], 1);
        csr_src[rowstart[d] + pos] = src[i];
    }
}

// ---------------- pre-scale: Xs[n,:] = x[n,:] * dinv[n] (layer-1 input only) ----------------
__global__ void prescale_kernel(const float* __restrict__ X, const float* __restrict__ dinv,
                                float* __restrict__ Xs, int d) {
    int node = blockIdx.x;
    int t = threadIdx.x;
    if (t < d) Xs[(size_t)node * d + t] = X[(size_t)node * d + t] * dinv[node];
}

// ---------------- weight split+transpose ----------------
__global__ void wsplit_kernel(const float* __restrict__ W, unsigned short* __restrict__ hi,
                              unsigned short* __restrict__ lo, int K, int N, int Kp) {
    int n = blockIdx.x, k = threadIdx.x;
    float v = (n < N && k < K) ? W[(size_t)k * N + n] : 0.0f;
    unsigned short h, l;
    split_f32(v, h, l);
    hi[(size_t)n * Kp + k] = h;
    lo[(size_t)n * Kp + k] = l;
}

// ---------------- aggregation v2: acc = dinv[n]*(Xs[n] + sum Xs[sr]); 8-way ILP ----------------
__global__ void agg_split_kernel(const float* __restrict__ Xs, const int* __restrict__ rowstart,
                                 const int* __restrict__ cnt, const int* __restrict__ csr_src,
                                 const float* __restrict__ dinv, unsigned short* __restrict__ ohi,
                                 unsigned short* __restrict__ olo, int d, int Kp) {
    int node = blockIdx.x;
    int t = threadIdx.x;
    if (t >= Kp) return;
    float acc = 0.0f;
    if (t < d) {
        int s = rowstart[node];
        int e = s + cnt[node];
        float a0 = Xs[(size_t)node * d + t], a1 = 0.f, a2 = 0.f, a3 = 0.f;
        int j = s;
        for (; j + 8 <= e; j += 8) {
            int i0 = csr_src[j],     i1 = csr_src[j + 1], i2 = csr_src[j + 2], i3 = csr_src[j + 3];
            int i4 = csr_src[j + 4], i5 = csr_src[j + 5], i6 = csr_src[j + 6], i7 = csr_src[j + 7];
            float x0 = Xs[(size_t)i0 * d + t], x1 = Xs[(size_t)i1 * d + t];
            float x2 = Xs[(size_t)i2 * d + t], x3 = Xs[(size_t)i3 * d + t];
            float x4 = Xs[(size_t)i4 * d + t], x5 = Xs[(size_t)i5 * d + t];
            float x6 = Xs[(size_t)i6 * d + t], x7 = Xs[(size_t)i7 * d + t];
            a0 += x0; a1 += x1; a2 += x2; a3 += x3;
            a0 += x4; a1 += x5; a2 += x6; a3 += x7;
        }
        for (; j + 4 <= e; j += 4) {
            int i0 = csr_src[j], i1 = csr_src[j + 1], i2 = csr_src[j + 2], i3 = csr_src[j + 3];
            float x0 = Xs[(size_t)i0 * d + t], x1 = Xs[(size_t)i1 * d + t];
            float x2 = Xs[(size_t)i2 * d + t], x3 = Xs[(size_t)i3 * d + t];
            a0 += x0; a1 += x1; a2 += x2; a3 += x3;
        }
        for (; j < e; j++) a0 += Xs[(size_t)csr_src[j] * d + t];
        acc = ((a0 + a1) + (a2 + a3)) * dinv[node];
    }
    unsigned short h, l;
    split_f32(acc, h, l);
    ohi[(size_t)node * Kp + t] = h;
    olo[(size_t)node * Kp + t] = l;
}

// ---------------- split-bf16 MFMA GEMM: C = post(A @ B + bias) ----------------
// post: relu then optional *scale[row] (pre-scales next layer's aggregation input)
__global__ __launch_bounds__(256) void mfma_gemm_kernel(
    const unsigned short* __restrict__ Ahi, const unsigned short* __restrict__ Alo,
    const unsigned short* __restrict__ Bhi, const unsigned short* __restrict__ Blo,
    const float* __restrict__ bias, const float* __restrict__ scale,
    float* __restrict__ C, int M, int N, int Kp, int nChunks, int do_relu)
{
    __shared__ __align__(16) unsigned short lds[4][4][64][8];   // 16 KB
    int t = threadIdx.x;
    int wv = t >> 6, ln = t & 63;
    int m0 = blockIdx.y * 64, n0 = blockIdx.x * 64;
    int q = ln >> 4, l16 = ln & 15;
    int wm = wv & 1, wn = wv >> 1;

    const unsigned short* garr = (wv == 0) ? Ahi : (wv == 1) ? Alo : (wv == 2) ? Bhi : Blo;
    int row0 = ((wv < 2) ? m0 : n0) + ln;

    f32x4 acc[2][2] = {};

    for (int ck = 0; ck < nChunks; ck++) {
        const unsigned short* g = garr + (size_t)row0 * Kp + ck * 32;
        #pragma unroll
        for (int qq = 0; qq < 4; qq++)
            gload_lds16(g + qq * 8, &lds[wv][qq][0][0]);
        __syncthreads();

        bf16x8 ah[2], al[2], bh[2], bl[2];
        #pragma unroll
        for (int i = 0; i < 2; i++) {
            int ra = wm * 32 + i * 16 + l16;
            int rb = wn * 32 + i * 16 + l16;
            ah[i] = *(const bf16x8*)&lds[0][q][ra][0];
            al[i] = *(const bf16x8*)&lds[1][q][ra][0];
            bh[i] = *(const bf16x8*)&lds[2][q][rb][0];
            bl[i] = *(const bf16x8*)&lds[3][q][rb][0];
        }
        #pragma unroll
        for (int i = 0; i < 2; i++)
            #pragma unroll
            for (int j = 0; j < 2; j++) {
                acc[i][j] = __builtin_amdgcn_mfma_f32_16x16x32_bf16(ah[i], bh[j], acc[i][j], 0, 0, 0);
                acc[i][j] = __builtin_amdgcn_mfma_f32_16x16x32_bf16(ah[i], bl[j], acc[i][j], 0, 0, 0);
                acc[i][j] = __builtin_amdgcn_mfma_f32_16x16x32_bf16(al[i], bh[j], acc[i][j], 0, 0, 0);
            }
        __syncthreads();
    }

    #pragma unroll
    for (int i = 0; i < 2; i++) {
        int rbase = m0 + wm * 32 + i * 16 + q * 4;
        #pragma unroll
        for (int j = 0; j < 2; j++) {
            int col = n0 + wn * 32 + j * 16 + l16;
            if (col >= N) continue;
            float bv = bias[col];
            #pragma unroll
            for (int r = 0; r < 4; r++) {
                int row = rbase + r;
                if (row < M) {
                    float v = acc[i][j][r] + bv;
                    if (do_relu) v = fmaxf(v, 0.0f);
                    if (scale) v *= scale[row];
                    C[(size_t)row * N + col] = v;
                }
            }
        }
    }
}

// ---------------- segment-max pool (batch sorted) ----------------
__device__ inline int lower_bound_dev(const int* a, int n, int v) {
    int lo = 0, hi = n;
    while (lo < hi) { int mid = (lo + hi) >> 1; if (a[mid] < v) lo = mid + 1; else hi = mid; }
    return lo;
}

__global__ void pool_kernel(const float* __restrict__ H, const int* __restrict__ batch,
                            float* __restrict__ pooled, int n, int d, int G) {
    int g = blockIdx.x;
    int t = threadIdx.x;
    int s = lower_bound_dev(batch, n, g);
    int e = lower_bound_dev(batch, n, g + 1);
    if (t >= d) return;
    float m = 0.0f;
    for (int i = s; i < e; i++) m = fmaxf(m, H[(size_t)i * d + t]);
    pooled[(size_t)g * d + t] = m;
}

// ---------------- fused FC ----------------
__global__ __launch_bounds__(256) void fc_fused_kernel(const float* __restrict__ pooled,
                                                       const float* __restrict__ Wf1,
                                                       const float* __restrict__ bf1,
                                                       const float* __restrict__ Wf2,
                                                       const float* __restrict__ bf2,
                                                       float* __restrict__ out) {
    __shared__ float pl[312];
    __shared__ float f1[1024];
    __shared__ float part[256];
    int g = blockIdx.x;
    int t = threadIdx.x;
    for (int i = t; i < 312; i += 256) pl[i] = pooled[(size_t)g * 312 + i];
    __syncthreads();

    float acc0 = 0.f, acc1 = 0.f, acc2 = 0.f, acc3 = 0.f;
    for (int k = 0; k < 312; k++) {
        float pk = pl[k];
        const float* w = Wf1 + (size_t)k * 1024 + t;
        acc0 += pk * w[0];
        acc1 += pk * w[256];
        acc2 += pk * w[512];
        acc3 += pk * w[768];
    }
    f1[t]       = fmaxf(acc0 + bf1[t], 0.f);
    f1[t + 256] = fmaxf(acc1 + bf1[t + 256], 0.f);
    f1[t + 512] = fmaxf(acc2 + bf1[t + 512], 0.f);
    f1[t + 768] = fmaxf(acc3 + bf1[t + 768], 0.f);
    __syncthreads();

    int n = t & 127;
    int h = t >> 7;
    float p = 0.f;
    const float* w2 = Wf2 + (size_t)h * 512 * 128 + n;
    const float* fl = f1 + h * 512;
    for (int k = 0; k < 512; k++) p += fl[k] * w2[(size_t)k * 128];
    part[t] = p;
    __syncthreads();
    if (t < 128) out[(size_t)g * 128 + t] = part[t] + part[t + 128] + bf2[t];
}

extern "C" void kernel_launch(void* const* d_in, const int* in_sizes, int n_in,
                              void* d_out, int out_size, void* d_ws, size_t ws_size,
                              hipStream_t stream) {
    const float* x    = (const float*)d_in[0];
    const int*   ei   = (const int*)d_in[1];
    const int*   batch= (const int*)d_in[2];
    const float* W1 = (const float*)d_in[3];  const float* b1  = (const float*)d_in[4];
    const float* W2 = (const float*)d_in[5];  const float* b2  = (const float*)d_in[6];
    const float* W3 = (const float*)d_in[7];  const float* b3  = (const float*)d_in[8];
    const float* Wf1= (const float*)d_in[9];  const float* bf1 = (const float*)d_in[10];
    const float* Wf2= (const float*)d_in[11]; const float* bf2 = (const float*)d_in[12];
    float* out = (float*)d_out;

    const int* srcp = ei;
    const int* dstp = ei + EDGES;

    char* p = (char*)d_ws;
    size_t o = 0;
    auto takeB = [&](size_t bytes) { char* q = p + o; o += (bytes + 255) & ~(size_t)255; return q; };
    int*   cnt      = (int*)takeB(NODES * 4);
    int*   cursor   = (int*)takeB(NODES * 4);
    int*   rowstart = (int*)takeB(NODES * 4);
    float* dinv     = (float*)takeB(NODES * 4);
    int*   csr_src  = (int*)takeB(EDGES * 4);
    unsigned short* aggH = (unsigned short*)takeB((size_t)MPAD * 160 * 2);
    unsigned short* aggL = (unsigned short*)takeB((size_t)MPAD * 160 * 2);
    float* xs     = (float*)takeB((size_t)NODES * 78 * 4);
    float* hbuf   = (float*)takeB((size_t)NODES * 312 * 4);
    float* pooled = (float*)takeB((size_t)GRAPHS * 312 * 4);
    unsigned short* Wt1h = (unsigned short*)takeB(128 * 96 * 2);
    unsigned short* Wt1l = (unsigned short*)takeB(128 * 96 * 2);
    unsigned short* Wt2h = (unsigned short*)takeB(192 * 96 * 2);
    unsigned short* Wt2l = (unsigned short*)takeB(192 * 96 * 2);
    unsigned short* Wt3h = (unsigned short*)takeB(320 * 160 * 2);
    unsigned short* Wt3l = (unsigned short*)takeB(320 * 160 * 2);
    (void)ws_size;

    hipMemsetAsync(cnt, 0, NODES * sizeof(int), stream);
    hipMemsetAsync(cursor, 0, NODES * sizeof(int), stream);

    wsplit_kernel<<<128, 96, 0, stream>>>(W1, Wt1h, Wt1l, 78, 78, 96);
    wsplit_kernel<<<192, 96, 0, stream>>>(W2, Wt2h, Wt2l, 78, 156, 96);
    wsplit_kernel<<<320, 160, 0, stream>>>(W3, Wt3h, Wt3l, 156, 312, 160);

    count_kernel<<<(EDGES + 255) / 256, 256, 0, stream>>>(dstp, cnt, EDGES);
    dinv_kernel<<<(NODES + 255) / 256, 256, 0, stream>>>(cnt, dinv, NODES);
    scan_kernel<<<1, 1024, 0, stream>>>(cnt, rowstart, NODES);
    fill_kernel<<<(EDGES + 255) / 256, 256, 0, stream>>>(srcp, dstp, rowstart, cursor, csr_src, EDGES);

    // layer 1: prescale x, agg, gemm (epilogue writes h1*dinv for next agg)
    prescale_kernel<<<NODES, 128, 0, stream>>>(x, dinv, xs, 78);
    agg_split_kernel<<<NODES, 128, 0, stream>>>(xs, rowstart, cnt, csr_src, dinv, aggH, aggL, 78, 96);
    mfma_gemm_kernel<<<dim3(2, MPAD / 64), 256, 0, stream>>>(aggH, aggL, Wt1h, Wt1l, b1, dinv, hbuf,
                                                             NODES, 78, 96, 3, 1);
    // layer 2 (input already pre-scaled)
    agg_split_kernel<<<NODES, 128, 0, stream>>>(hbuf, rowstart, cnt, csr_src, dinv, aggH, aggL, 78, 96);
    mfma_gemm_kernel<<<dim3(3, MPAD / 64), 256, 0, stream>>>(aggH, aggL, Wt2h, Wt2l, b2, dinv, hbuf,
                                                             NODES, 156, 96, 3, 1);
    // layer 3 (unscaled output for pooling)
    agg_split_kernel<<<NODES, 192, 0, stream>>>(hbuf, rowstart, cnt, csr_src, dinv, aggH, aggL, 156, 160);
    mfma_gemm_kernel<<<dim3(5, MPAD / 64), 256, 0, stream>>>(aggH, aggL, Wt3h, Wt3l, b3, nullptr, hbuf,
                                                             NODES, 312, 160, 5, 1);

    pool_kernel<<<GRAPHS, 320, 0, stream>>>(hbuf, batch, pooled, NODES, 312, GRAPHS);
    fc_fused_kernel<<<GRAPHS, 256, 0, stream>>>(pooled, Wf1, bf1, Wf2, bf2, out);
}

// Round 5
// 407.675 us; speedup vs baseline: 2.0423x; 1.0565x over previous
//
#include <hip/hip_runtime.h>

#define NODES  30000
#define EDGES  480000
#define GRAPHS 500
#define MPAD   30016   // 64*469

typedef __bf16 bf16x8 __attribute__((ext_vector_type(8)));
typedef float  f32x4  __attribute__((ext_vector_type(4)));

// ---------------- fp32 -> bf16 hi/lo split (RNE both halves) ----------------
__device__ __forceinline__ void split_f32(float a, unsigned short& hi, unsigned short& lo) {
    unsigned int u = __float_as_uint(a);
    unsigned int rh = (u + 0x7fffu + ((u >> 16) & 1u)) & 0xffff0000u;
    hi = (unsigned short)(rh >> 16);
    float l = a - __uint_as_float(rh);
    unsigned int ul = __float_as_uint(l);
    lo = (unsigned short)((ul + 0x7fffu + ((ul >> 16) & 1u)) >> 16);
}

__device__ __forceinline__ void gload_lds16(const void* g, void* l) {
    __builtin_amdgcn_global_load_lds(
        (__attribute__((address_space(1))) void*)g,
        (__attribute__((address_space(3))) void*)l, 16, 0, 0);
}

// ---------------- CSR build ----------------
__global__ void count_kernel(const int* __restrict__ dst, int* __restrict__ cnt, int E) {
    int i = blockIdx.x * blockDim.x + threadIdx.x;
    if (i < E) atomicAdd(&cnt[dst[i]], 1);
}

__global__ void dinv_kernel(const int* __restrict__ cnt, float* __restrict__ dinv, int N) {
    int i = blockIdx.x * blockDim.x + threadIdx.x;
    if (i < N) dinv[i] = rsqrtf((float)cnt[i] + 1.0f);
}

__global__ void scan_kernel(const int* __restrict__ cnt, int* __restrict__ rowstart, int n) {
    __shared__ int buf[1024];
    __shared__ int carry;
    if (threadIdx.x == 0) carry = 0;
    __syncthreads();
    const int PT = 8;
    for (int base = 0; base < n; base += 1024 * PT) {
        int v[PT]; int sum = 0;
        int i0 = base + (int)threadIdx.x * PT;
        #pragma unroll
        for (int j = 0; j < PT; j++) { int idx = i0 + j; int x = (idx < n) ? cnt[idx] : 0; v[j] = x; sum += x; }
        buf[threadIdx.x] = sum;
        __syncthreads();
        for (int ofs = 1; ofs < 1024; ofs <<= 1) {
            int t = (threadIdx.x >= (unsigned)ofs) ? buf[threadIdx.x - ofs] : 0;
            __syncthreads();
            buf[threadIdx.x] += t;
            __syncthreads();
        }
        int excl = buf[threadIdx.x] - sum + carry;
        #pragma unroll
        for (int j = 0; j < PT; j++) { int idx = i0 + j; if (idx < n) rowstart[idx] = excl; excl += v[j]; }
        __syncthreads();
        if (threadIdx.x == 1023) carry += buf[1023];
        __syncthreads();
    }
}

__global__ void fill_kernel(const int* __restrict__ src, const int* __restrict__ dst,
                            const int* __restrict__ rowstart, int* __restrict__ cursor,
                            int* __restrict__ csr_src, int E) {
    int i = blockIdx.x * blockDim.x + threadIdx.x;
    if (i < E) {
        int d = dst[i];
        int pos = atomicAdd(&cursor[d], 1);
        csr_src[rowstart[d] + pos] = src[i];
    }
}

// ---------------- pre-scale (flat, coalesced): Xs[i] = X[i] * dinv[i/78] ----------------
__global__ void prescale_kernel(const float* __restrict__ X, const float* __restrict__ dinv,
                                float* __restrict__ Xs, int total) {
    int i = blockIdx.x * blockDim.x + threadIdx.x;
    if (i < total) Xs[i] = X[i] * dinv[i / 78];
}

// ---------------- weight split+transpose ----------------
__global__ void wsplit_kernel(const float* __restrict__ W, unsigned short* __restrict__ hi,
                              unsigned short* __restrict__ lo, int K, int N, int Kp) {
    int n = blockIdx.x, k = threadIdx.x;
    float v = (n < N && k < K) ? W[(size_t)k * N + n] : 0.0f;
    unsigned short h, l;
    split_f32(v, h, l);
    hi[(size_t)n * Kp + k] = h;
    lo[(size_t)n * Kp + k] = l;
}

// ---------------- aggregation: acc = dinv[n]*(Xs[n] + sum Xs[sr]); 8-way ILP ----------------
__global__ void agg_split_kernel(const float* __restrict__ Xs, const int* __restrict__ rowstart,
                                 const int* __restrict__ cnt, const int* __restrict__ csr_src,
                                 const float* __restrict__ dinv, unsigned short* __restrict__ ohi,
                                 unsigned short* __restrict__ olo, int d, int Kp) {
    int node = blockIdx.x;
    int t = threadIdx.x;
    if (t >= Kp) return;
    float acc = 0.0f;
    if (t < d) {
        int s = rowstart[node];
        int e = s + cnt[node];
        float a0 = Xs[(size_t)node * d + t], a1 = 0.f, a2 = 0.f, a3 = 0.f;
        int j = s;
        for (; j + 8 <= e; j += 8) {
            int i0 = csr_src[j],     i1 = csr_src[j + 1], i2 = csr_src[j + 2], i3 = csr_src[j + 3];
            int i4 = csr_src[j + 4], i5 = csr_src[j + 5], i6 = csr_src[j + 6], i7 = csr_src[j + 7];
            float x0 = Xs[(size_t)i0 * d + t], x1 = Xs[(size_t)i1 * d + t];
            float x2 = Xs[(size_t)i2 * d + t], x3 = Xs[(size_t)i3 * d + t];
            float x4 = Xs[(size_t)i4 * d + t], x5 = Xs[(size_t)i5 * d + t];
            float x6 = Xs[(size_t)i6 * d + t], x7 = Xs[(size_t)i7 * d + t];
            a0 += x0; a1 += x1; a2 += x2; a3 += x3;
            a0 += x4; a1 += x5; a2 += x6; a3 += x7;
        }
        for (; j + 4 <= e; j += 4) {
            int i0 = csr_src[j], i1 = csr_src[j + 1], i2 = csr_src[j + 2], i3 = csr_src[j + 3];
            float x0 = Xs[(size_t)i0 * d + t], x1 = Xs[(size_t)i1 * d + t];
            float x2 = Xs[(size_t)i2 * d + t], x3 = Xs[(size_t)i3 * d + t];
            a0 += x0; a1 += x1; a2 += x2; a3 += x3;
        }
        for (; j < e; j++) a0 += Xs[(size_t)csr_src[j] * d + t];
        acc = ((a0 + a1) + (a2 + a3)) * dinv[node];
    }
    unsigned short h, l;
    split_f32(acc, h, l);
    ohi[(size_t)node * Kp + t] = h;
    olo[(size_t)node * Kp + t] = l;
}

// ---------------- split-bf16 MFMA GEMM v2: row-persistent, in-kernel column loop ----------------
// A hi/lo [MPAD][Kp] staged ONCE to LDS (whole K extent); loop over 64-col B tiles.
// LDS cell layout per operand: [plane(2)][chunk(NCK)][q(4)][row(64)][8 bf16].
// Block: 256 thr / 4 waves; wave w -> 32x32 subtile (wm=w&1, wn=w>>1).
template <int NCK>
__global__ __launch_bounds__(256) void mfma_gemm_v2(
    const unsigned short* __restrict__ Ahi, const unsigned short* __restrict__ Alo,
    const unsigned short* __restrict__ Bhi, const unsigned short* __restrict__ Blo,
    const float* __restrict__ bias, const float* __restrict__ scale,
    float* __restrict__ C, int M, int N, int nN, int do_relu)
{
    constexpr int Kp = NCK * 32;
    constexpr int CELLS = NCK * 256;          // 16B cells per plane
    extern __shared__ unsigned short smem[];
    unsigned short* sA = smem;                 // 2*NCK*2048 elems
    unsigned short* sB = smem + 2 * CELLS * 8;

    int t = threadIdx.x;
    int wv = t >> 6, ln = t & 63;
    int q = ln >> 4, l16 = ln & 15;
    int wm = wv & 1, wn = wv >> 1;
    int m0 = blockIdx.x * 64;

    // ---- stage A (all chunks, both planes) ----
    #pragma unroll
    for (int i = 0; i < 2 * NCK; i++) {
        int c = i * 256 + t;
        int plane = c / CELLS;
        int r = c - plane * CELLS;
        int ck = r >> 8, qq = (r >> 6) & 3, row = r & 63;
        const unsigned short* src = (plane ? Alo : Ahi) + (size_t)(m0 + row) * Kp + ck * 32 + qq * 8;
        gload_lds16(src, &sA[(size_t)c * 8]);
    }

    for (int nt = 0; nt < nN; nt++) {
        int n0 = nt * 64;
        if (nt > 0) __syncthreads();           // all waves done reading old B
        // ---- stage B tile ----
        #pragma unroll
        for (int i = 0; i < 2 * NCK; i++) {
            int c = i * 256 + t;
            int plane = c / CELLS;
            int r = c - plane * CELLS;
            int ck = r >> 8, qq = (r >> 6) & 3, row = r & 63;
            const unsigned short* src = (plane ? Blo : Bhi) + (size_t)(n0 + row) * Kp + ck * 32 + qq * 8;
            gload_lds16(src, &sB[(size_t)c * 8]);
        }
        __syncthreads();                        // drains DMA (vmcnt0 before barrier)

        f32x4 acc[2][2] = {};
        #pragma unroll
        for (int ck = 0; ck < NCK; ck++) {
            bf16x8 ah[2], al[2], bh[2], bl[2];
            #pragma unroll
            for (int i = 0; i < 2; i++) {
                int ra = wm * 32 + i * 16 + l16;
                int rb = wn * 32 + i * 16 + l16;
                ah[i] = *(const bf16x8*)&sA[(size_t)(((0 * NCK + ck) * 4 + q) * 64 + ra) * 8];
                al[i] = *(const bf16x8*)&sA[(size_t)(((1 * NCK + ck) * 4 + q) * 64 + ra) * 8];
                bh[i] = *(const bf16x8*)&sB[(size_t)(((0 * NCK + ck) * 4 + q) * 64 + rb) * 8];
                bl[i] = *(const bf16x8*)&sB[(size_t)(((1 * NCK + ck) * 4 + q) * 64 + rb) * 8];
            }
            #pragma unroll
            for (int i = 0; i < 2; i++)
                #pragma unroll
                for (int j = 0; j < 2; j++) {
                    acc[i][j] = __builtin_amdgcn_mfma_f32_16x16x32_bf16(ah[i], bh[j], acc[i][j], 0, 0, 0);
                    acc[i][j] = __builtin_amdgcn_mfma_f32_16x16x32_bf16(ah[i], bl[j], acc[i][j], 0, 0, 0);
                    acc[i][j] = __builtin_amdgcn_mfma_f32_16x16x32_bf16(al[i], bh[j], acc[i][j], 0, 0, 0);
                }
        }

        // epilogue: C/D layout col=lane&15, row=(lane>>4)*4+reg
        #pragma unroll
        for (int i = 0; i < 2; i++) {
            int rbase = m0 + wm * 32 + i * 16 + q * 4;
            #pragma unroll
            for (int j = 0; j < 2; j++) {
                int col = n0 + wn * 32 + j * 16 + l16;
                if (col >= N) continue;
                float bv = bias[col];
                #pragma unroll
                for (int r = 0; r < 4; r++) {
                    int row = rbase + r;
                    if (row < M) {
                        float v = acc[i][j][r] + bv;
                        if (do_relu) v = fmaxf(v, 0.0f);
                        if (scale) v *= scale[row];
                        C[(size_t)row * N + col] = v;
                    }
                }
            }
        }
    }
}

// ---------------- segment-max pool (batch sorted) ----------------
__device__ inline int lower_bound_dev(const int* a, int n, int v) {
    int lo = 0, hi = n;
    while (lo < hi) { int mid = (lo + hi) >> 1; if (a[mid] < v) lo = mid + 1; else hi = mid; }
    return lo;
}

__global__ void pool_kernel(const float* __restrict__ H, const int* __restrict__ batch,
                            float* __restrict__ pooled, int n, int d, int G) {
    int g = blockIdx.x;
    int t = threadIdx.x;
    int s = lower_bound_dev(batch, n, g);
    int e = lower_bound_dev(batch, n, g + 1);
    if (t >= d) return;
    float m = 0.0f;
    for (int i = s; i < e; i++) m = fmaxf(m, H[(size_t)i * d + t]);
    pooled[(size_t)g * d + t] = m;
}

// ---------------- fused FC ----------------
__global__ __launch_bounds__(256) void fc_fused_kernel(const float* __restrict__ pooled,
                                                       const float* __restrict__ Wf1,
                                                       const float* __restrict__ bf1,
                                                       const float* __restrict__ Wf2,
                                                       const float* __restrict__ bf2,
                                                       float* __restrict__ out) {
    __shared__ float pl[312];
    __shared__ float f1[1024];
    __shared__ float part[256];
    int g = blockIdx.x;
    int t = threadIdx.x;
    for (int i = t; i < 312; i += 256) pl[i] = pooled[(size_t)g * 312 + i];
    __syncthreads();

    float acc0 = 0.f, acc1 = 0.f, acc2 = 0.f, acc3 = 0.f;
    for (int k = 0; k < 312; k++) {
        float pk = pl[k];
        const float* w = Wf1 + (size_t)k * 1024 + t;
        acc0 += pk * w[0];
        acc1 += pk * w[256];
        acc2 += pk * w[512];
        acc3 += pk * w[768];
    }
    f1[t]       = fmaxf(acc0 + bf1[t], 0.f);
    f1[t + 256] = fmaxf(acc1 + bf1[t + 256], 0.f);
    f1[t + 512] = fmaxf(acc2 + bf1[t + 512], 0.f);
    f1[t + 768] = fmaxf(acc3 + bf1[t + 768], 0.f);
    __syncthreads();

    int n = t & 127;
    int h = t >> 7;
    float p = 0.f;
    const float* w2 = Wf2 + (size_t)h * 512 * 128 + n;
    const float* fl = f1 + h * 512;
    for (int k = 0; k < 512; k++) p += fl[k] * w2[(size_t)k * 128];
    part[t] = p;
    __syncthreads();
    if (t < 128) out[(size_t)g * 128 + t] = part[t] + part[t + 128] + bf2[t];
}

extern "C" void kernel_launch(void* const* d_in, const int* in_sizes, int n_in,
                              void* d_out, int out_size, void* d_ws, size_t ws_size,
                              hipStream_t stream) {
    const float* x    = (const float*)d_in[0];
    const int*   ei   = (const int*)d_in[1];
    const int*   batch= (const int*)d_in[2];
    const float* W1 = (const float*)d_in[3];  const float* b1  = (const float*)d_in[4];
    const float* W2 = (const float*)d_in[5];  const float* b2  = (const float*)d_in[6];
    const float* W3 = (const float*)d_in[7];  const float* b3  = (const float*)d_in[8];
    const float* Wf1= (const float*)d_in[9];  const float* bf1 = (const float*)d_in[10];
    const float* Wf2= (const float*)d_in[11]; const float* bf2 = (const float*)d_in[12];
    float* out = (float*)d_out;

    const int* srcp = ei;
    const int* dstp = ei + EDGES;

    char* p = (char*)d_ws;
    size_t o = 0;
    auto takeB = [&](size_t bytes) { char* q = p + o; o += (bytes + 255) & ~(size_t)255; return q; };
    int*   cnt      = (int*)takeB(NODES * 4);
    int*   cursor   = (int*)takeB(NODES * 4);
    int*   rowstart = (int*)takeB(NODES * 4);
    float* dinv     = (float*)takeB(NODES * 4);
    int*   csr_src  = (int*)takeB(EDGES * 4);
    unsigned short* aggH = (unsigned short*)takeB((size_t)MPAD * 160 * 2);
    unsigned short* aggL = (unsigned short*)takeB((size_t)MPAD * 160 * 2);
    float* xs     = (float*)takeB((size_t)NODES * 78 * 4);
    float* hbuf   = (float*)takeB((size_t)NODES * 312 * 4);
    float* pooled = (float*)takeB((size_t)GRAPHS * 312 * 4);
    unsigned short* Wt1h = (unsigned short*)takeB(128 * 96 * 2);
    unsigned short* Wt1l = (unsigned short*)takeB(128 * 96 * 2);
    unsigned short* Wt2h = (unsigned short*)takeB(192 * 96 * 2);
    unsigned short* Wt2l = (unsigned short*)takeB(192 * 96 * 2);
    unsigned short* Wt3h = (unsigned short*)takeB(320 * 160 * 2);
    unsigned short* Wt3l = (unsigned short*)takeB(320 * 160 * 2);
    (void)ws_size;

    hipMemsetAsync(cnt, 0, NODES * sizeof(int), stream);
    hipMemsetAsync(cursor, 0, NODES * sizeof(int), stream);

    wsplit_kernel<<<128, 96, 0, stream>>>(W1, Wt1h, Wt1l, 78, 78, 96);
    wsplit_kernel<<<192, 96, 0, stream>>>(W2, Wt2h, Wt2l, 78, 156, 96);
    wsplit_kernel<<<320, 160, 0, stream>>>(W3, Wt3h, Wt3l, 156, 312, 160);

    count_kernel<<<(EDGES + 255) / 256, 256, 0, stream>>>(dstp, cnt, EDGES);
    dinv_kernel<<<(NODES + 255) / 256, 256, 0, stream>>>(cnt, dinv, NODES);
    scan_kernel<<<1, 1024, 0, stream>>>(cnt, rowstart, NODES);
    fill_kernel<<<(EDGES + 255) / 256, 256, 0, stream>>>(srcp, dstp, rowstart, cursor, csr_src, EDGES);

    const int NBLK = MPAD / 64;   // 469

    // layer 1
    prescale_kernel<<<(NODES * 78 + 255) / 256, 256, 0, stream>>>(x, dinv, xs, NODES * 78);
    agg_split_kernel<<<NODES, 128, 0, stream>>>(xs, rowstart, cnt, csr_src, dinv, aggH, aggL, 78, 96);
    mfma_gemm_v2<3><<<NBLK, 256, 3 * 16384, stream>>>(aggH, aggL, Wt1h, Wt1l, b1, dinv, hbuf,
                                                      NODES, 78, 2, 1);
    // layer 2
    agg_split_kernel<<<NODES, 128, 0, stream>>>(hbuf, rowstart, cnt, csr_src, dinv, aggH, aggL, 78, 96);
    mfma_gemm_v2<3><<<NBLK, 256, 3 * 16384, stream>>>(aggH, aggL, Wt2h, Wt2l, b2, dinv, hbuf,
                                                      NODES, 156, 3, 1);
    // layer 3 (unscaled output for pooling)
    agg_split_kernel<<<NODES, 192, 0, stream>>>(hbuf, rowstart, cnt, csr_src, dinv, aggH, aggL, 156, 160);
    mfma_gemm_v2<5><<<NBLK, 256, 5 * 16384, stream>>>(aggH, aggL, Wt3h, Wt3l, b3, nullptr, hbuf,
                                                      NODES, 312, 5, 1);

    pool_kernel<<<GRAPHS, 320, 0, stream>>>(hbuf, batch, pooled, NODES, 312, GRAPHS);
    fc_fused_kernel<<<GRAPHS, 256, 0, stream>>>(pooled, Wf1, bf1, Wf2, bf2, out);
}

// Round 7
// 393.534 us; speedup vs baseline: 2.1157x; 1.0359x over previous
//
#include <hip/hip_runtime.h>

#define NODES  30000
#define EDGES  480000
#define GRAPHS 500
#define MPAD   30016   // 64*469

typedef __bf16 bf16x8 __attribute__((ext_vector_type(8)));
typedef float  f32x4  __attribute__((ext_vector_type(4)));

__device__ __forceinline__ float4 f4add(float4 a, float4 b) {
    a.x += b.x; a.y += b.y; a.z += b.z; a.w += b.w; return a;
}

// ---------------- fp32 -> bf16 hi/lo split (RNE both halves) ----------------
__device__ __forceinline__ void split_f32(float a, unsigned short& hi, unsigned short& lo) {
    unsigned int u = __float_as_uint(a);
    unsigned int rh = (u + 0x7fffu + ((u >> 16) & 1u)) & 0xffff0000u;
    hi = (unsigned short)(rh >> 16);
    float l = a - __uint_as_float(rh);
    unsigned int ul = __float_as_uint(l);
    lo = (unsigned short)((ul + 0x7fffu + ((ul >> 16) & 1u)) >> 16);
}

__device__ __forceinline__ void gload_lds16(const void* g, void* l) {
    __builtin_amdgcn_global_load_lds(
        (__attribute__((address_space(1))) void*)g,
        (__attribute__((address_space(3))) void*)l, 16, 0, 0);
}

// ---------------- CSR build ----------------
__global__ void count_kernel(const int* __restrict__ dst, int* __restrict__ cnt, int E) {
    int i = blockIdx.x * blockDim.x + threadIdx.x;
    if (i < E) atomicAdd(&cnt[dst[i]], 1);
}

__global__ void dinv_kernel(const int* __restrict__ cnt, float* __restrict__ dinv, int N) {
    int i = blockIdx.x * blockDim.x + threadIdx.x;
    if (i < N) dinv[i] = rsqrtf((float)cnt[i] + 1.0f);
}

__global__ void scan_kernel(const int* __restrict__ cnt, int* __restrict__ rowstart, int n) {
    __shared__ int buf[1024];
    __shared__ int carry;
    if (threadIdx.x == 0) carry = 0;
    __syncthreads();
    const int PT = 8;
    for (int base = 0; base < n; base += 1024 * PT) {
        int v[PT]; int sum = 0;
        int i0 = base + (int)threadIdx.x * PT;
        #pragma unroll
        for (int j = 0; j < PT; j++) { int idx = i0 + j; int x = (idx < n) ? cnt[idx] : 0; v[j] = x; sum += x; }
        buf[threadIdx.x] = sum;
        __syncthreads();
        for (int ofs = 1; ofs < 1024; ofs <<= 1) {
            int t = (threadIdx.x >= (unsigned)ofs) ? buf[threadIdx.x - ofs] : 0;
            __syncthreads();
            buf[threadIdx.x] += t;
            __syncthreads();
        }
        int excl = buf[threadIdx.x] - sum + carry;
        #pragma unroll
        for (int j = 0; j < PT; j++) { int idx = i0 + j; if (idx < n) rowstart[idx] = excl; excl += v[j]; }
        __syncthreads();
        if (threadIdx.x == 1023) carry += buf[1023];
        __syncthreads();
    }
}

__global__ void fill_kernel(const int* __restrict__ src, const int* __restrict__ dst,
                            const int* __restrict__ rowstart, int* __restrict__ cursor,
                            int* __restrict__ csr_src, int E) {
    int i = blockIdx.x * blockDim.x + threadIdx.x;
    if (i < E) {
        int d = dst[i];
        int pos = atomicAdd(&cursor[d], 1);
        csr_src[rowstart[d] + pos] = src[i];
    }
}

// ---------------- pre-scale into padded stride-80 layout ----------------
__global__ void prescale_kernel(const float* __restrict__ X, const float* __restrict__ dinv,
                                float* __restrict__ Xs, int total) {
    int i = blockIdx.x * blockDim.x + threadIdx.x;
    if (i < total) {
        int node = i / 80;
        int c = i - node * 80;
        Xs[i] = (c < 78) ? X[node * 78 + c] * dinv[node] : 0.0f;
    }
}

// ---------------- weight split+transpose ----------------
__global__ void wsplit_kernel(const float* __restrict__ W, unsigned short* __restrict__ hi,
                              unsigned short* __restrict__ lo, int K, int N, int Kp) {
    int n = blockIdx.x, k = threadIdx.x;
    float v = (n < N && k < K) ? W[(size_t)k * N + n] : 0.0f;
    unsigned short h, l;
    split_f32(v, h, l);
    hi[(size_t)n * Kp + k] = h;
    lo[(size_t)n * Kp + k] = l;
}

// ---------------- aggregation v3: float4 gathers, EPI edges per instruction ----------------
// Xs rows padded to DV float4 (pad cols zero). One node per 64-lane wave; lane owns 4 cols.
// EPI = 64/DV edge slots per gather round. Cross-slot reduce: ALL shuffle sources read
// BEFORE any accumulation (sequential update caused round-6's wraparound contamination).
template <int DV, int KQ>
__global__ __launch_bounds__(256) void agg_split_v3(
    const float* __restrict__ Xs, const int* __restrict__ rowstart,
    const int* __restrict__ cnt, const int* __restrict__ csr_src,
    const float* __restrict__ dinv,
    unsigned short* __restrict__ ohi, unsigned short* __restrict__ olo)
{
    constexpr int EPI = 64 / DV;
    constexpr int Kp = KQ * 4;
    int node = blockIdx.x * 4 + (threadIdx.x >> 6);
    int lane = threadIdx.x & 63;
    int sub = lane / DV;
    int c4 = lane - sub * DV;
    const float4* X4 = (const float4*)Xs;

    float4 acc0 = {0.f, 0.f, 0.f, 0.f}, acc1 = {0.f, 0.f, 0.f, 0.f};
    int s = rowstart[node];
    int e = s + cnt[node];

    if (sub < EPI) {
        if (sub == 0) acc0 = X4[(size_t)node * DV + c4];   // self term
        int j = s;
        for (; j + 4 * EPI <= e; j += 4 * EPI) {
            int i0 = csr_src[j + sub];
            int i1 = csr_src[j + EPI + sub];
            int i2 = csr_src[j + 2 * EPI + sub];
            int i3 = csr_src[j + 3 * EPI + sub];
            float4 x0 = X4[(size_t)i0 * DV + c4];
            float4 x1 = X4[(size_t)i1 * DV + c4];
            float4 x2 = X4[(size_t)i2 * DV + c4];
            float4 x3 = X4[(size_t)i3 * DV + c4];
            acc0 = f4add(acc0, f4add(x0, x2));
            acc1 = f4add(acc1, f4add(x1, x3));
        }
        for (; j < e; j += EPI) {
            int jj = j + sub;
            if (jj < e) {
                int idx = csr_src[jj];
                acc0 = f4add(acc0, X4[(size_t)idx * DV + c4]);
            }
        }
    }
    float4 acc = f4add(acc0, acc1);

    if constexpr (EPI > 1) {
        // read ALL sources from the pre-reduction acc, then sum (valid for lanes < DV:
        // sources are lanes lane+DV, lane+2*DV, ... < 64 — no wraparound, no RAW hazard)
        float sx[EPI - 1], sy[EPI - 1], sz[EPI - 1], sw[EPI - 1];
        #pragma unroll
        for (int sft = 1; sft < EPI; sft++) {
            sx[sft - 1] = __shfl(acc.x, lane + sft * DV);
            sy[sft - 1] = __shfl(acc.y, lane + sft * DV);
            sz[sft - 1] = __shfl(acc.z, lane + sft * DV);
            sw[sft - 1] = __shfl(acc.w, lane + sft * DV);
        }
        #pragma unroll
        for (int sft = 1; sft < EPI; sft++) {
            acc.x += sx[sft - 1];
            acc.y += sy[sft - 1];
            acc.z += sz[sft - 1];
            acc.w += sw[sft - 1];
        }
    }

    if (lane < DV) {
        float di = dinv[node];
        ushort4 h4, l4;
        split_f32(acc.x * di, h4.x, l4.x);
        split_f32(acc.y * di, h4.y, l4.y);
        split_f32(acc.z * di, h4.z, l4.z);
        split_f32(acc.w * di, h4.w, l4.w);
        *(ushort4*)&ohi[(size_t)node * Kp + lane * 4] = h4;
        *(ushort4*)&olo[(size_t)node * Kp + lane * 4] = l4;
    } else if (lane < KQ) {
        ushort4 z = {0, 0, 0, 0};
        *(ushort4*)&ohi[(size_t)node * Kp + lane * 4] = z;
        *(ushort4*)&olo[(size_t)node * Kp + lane * 4] = z;
    }
}

// ---------------- split-bf16 MFMA GEMM v2: row-persistent, in-kernel column loop ----------------
template <int NCK>
__global__ __launch_bounds__(256) void mfma_gemm_v2(
    const unsigned short* __restrict__ Ahi, const unsigned short* __restrict__ Alo,
    const unsigned short* __restrict__ Bhi, const unsigned short* __restrict__ Blo,
    const float* __restrict__ bias, const float* __restrict__ scale,
    float* __restrict__ C, int M, int N, int Cstride, int nN, int do_relu)
{
    constexpr int Kp = NCK * 32;
    constexpr int CELLS = NCK * 256;
    extern __shared__ unsigned short smem[];
    unsigned short* sA = smem;
    unsigned short* sB = smem + 2 * CELLS * 8;

    int t = threadIdx.x;
    int wv = t >> 6, ln = t & 63;
    int q = ln >> 4, l16 = ln & 15;
    int wm = wv & 1, wn = wv >> 1;
    int m0 = blockIdx.x * 64;

    #pragma unroll
    for (int i = 0; i < 2 * NCK; i++) {
        int c = i * 256 + t;
        int plane = c / CELLS;
        int r = c - plane * CELLS;
        int ck = r >> 8, qq = (r >> 6) & 3, row = r & 63;
        const unsigned short* src = (plane ? Alo : Ahi) + (size_t)(m0 + row) * Kp + ck * 32 + qq * 8;
        gload_lds16(src, &sA[(size_t)c * 8]);
    }

    for (int nt = 0; nt < nN; nt++) {
        int n0 = nt * 64;
        if (nt > 0) __syncthreads();
        #pragma unroll
        for (int i = 0; i < 2 * NCK; i++) {
            int c = i * 256 + t;
            int plane = c / CELLS;
            int r = c - plane * CELLS;
            int ck = r >> 8, qq = (r >> 6) & 3, row = r & 63;
            const unsigned short* src = (plane ? Blo : Bhi) + (size_t)(n0 + row) * Kp + ck * 32 + qq * 8;
            gload_lds16(src, &sB[(size_t)c * 8]);
        }
        __syncthreads();

        f32x4 acc[2][2] = {};
        #pragma unroll
        for (int ck = 0; ck < NCK; ck++) {
            bf16x8 ah[2], al[2], bh[2], bl[2];
            #pragma unroll
            for (int i = 0; i < 2; i++) {
                int ra = wm * 32 + i * 16 + l16;
                int rb = wn * 32 + i * 16 + l16;
                ah[i] = *(const bf16x8*)&sA[(size_t)(((0 * NCK + ck) * 4 + q) * 64 + ra) * 8];
                al[i] = *(const bf16x8*)&sA[(size_t)(((1 * NCK + ck) * 4 + q) * 64 + ra) * 8];
                bh[i] = *(const bf16x8*)&sB[(size_t)(((0 * NCK + ck) * 4 + q) * 64 + rb) * 8];
                bl[i] = *(const bf16x8*)&sB[(size_t)(((1 * NCK + ck) * 4 + q) * 64 + rb) * 8];
            }
            #pragma unroll
            for (int i = 0; i < 2; i++)
                #pragma unroll
                for (int j = 0; j < 2; j++) {
                    acc[i][j] = __builtin_amdgcn_mfma_f32_16x16x32_bf16(ah[i], bh[j], acc[i][j], 0, 0, 0);
                    acc[i][j] = __builtin_amdgcn_mfma_f32_16x16x32_bf16(ah[i], bl[j], acc[i][j], 0, 0, 0);
                    acc[i][j] = __builtin_amdgcn_mfma_f32_16x16x32_bf16(al[i], bh[j], acc[i][j], 0, 0, 0);
                }
        }

        #pragma unroll
        for (int i = 0; i < 2; i++) {
            int rbase = m0 + wm * 32 + i * 16 + q * 4;
            #pragma unroll
            for (int j = 0; j < 2; j++) {
                int col = n0 + wn * 32 + j * 16 + l16;
                if (col >= Cstride) continue;
                float bv = (col < N) ? bias[col] : 0.0f;
                #pragma unroll
                for (int r = 0; r < 4; r++) {
                    int row = rbase + r;
                    if (row < M) {
                        float v = 0.0f;
                        if (col < N) {
                            v = acc[i][j][r] + bv;
                            if (do_relu) v = fmaxf(v, 0.0f);
                            if (scale) v *= scale[row];
                        }
                        C[(size_t)row * Cstride + col] = v;
                    }
                }
            }
        }
    }
}

// ---------------- segment-max pool (batch sorted), float4 ----------------
__device__ inline int lower_bound_dev(const int* a, int n, int v) {
    int lo = 0, hi = n;
    while (lo < hi) { int mid = (lo + hi) >> 1; if (a[mid] < v) lo = mid + 1; else hi = mid; }
    return lo;
}

__global__ void pool_kernel(const float* __restrict__ H, const int* __restrict__ batch,
                            float* __restrict__ pooled, int n, int G) {
    int g = blockIdx.x;
    int t = threadIdx.x;
    int s = lower_bound_dev(batch, n, g);
    int e = lower_bound_dev(batch, n, g + 1);
    if (t >= 78) return;
    const float4* H4 = (const float4*)H;
    float4 m = {0.f, 0.f, 0.f, 0.f};
    for (int i = s; i < e; i++) {
        float4 v = H4[(size_t)i * 78 + t];
        m.x = fmaxf(m.x, v.x); m.y = fmaxf(m.y, v.y);
        m.z = fmaxf(m.z, v.z); m.w = fmaxf(m.w, v.w);
    }
    ((float4*)pooled)[(size_t)g * 78 + t] = m;
}

// ---------------- fused FC ----------------
__global__ __launch_bounds__(256) void fc_fused_kernel(const float* __restrict__ pooled,
                                                       const float* __restrict__ Wf1,
                                                       const float* __restrict__ bf1,
                                                       const float* __restrict__ Wf2,
                                                       const float* __restrict__ bf2,
                                                       float* __restrict__ out) {
    __shared__ float pl[312];
    __shared__ float f1[1024];
    __shared__ float part[256];
    int g = blockIdx.x;
    int t = threadIdx.x;
    for (int i = t; i < 312; i += 256) pl[i] = pooled[(size_t)g * 312 + i];
    __syncthreads();

    float acc0 = 0.f, acc1 = 0.f, acc2 = 0.f, acc3 = 0.f;
    for (int k = 0; k < 312; k++) {
        float pk = pl[k];
        const float* w = Wf1 + (size_t)k * 1024 + t;
        acc0 += pk * w[0];
        acc1 += pk * w[256];
        acc2 += pk * w[512];
        acc3 += pk * w[768];
    }
    f1[t]       = fmaxf(acc0 + bf1[t], 0.f);
    f1[t + 256] = fmaxf(acc1 + bf1[t + 256], 0.f);
    f1[t + 512] = fmaxf(acc2 + bf1[t + 512], 0.f);
    f1[t + 768] = fmaxf(acc3 + bf1[t + 768], 0.f);
    __syncthreads();

    int n = t & 127;
    int h = t >> 7;
    float p = 0.f;
    const float* w2 = Wf2 + (size_t)h * 512 * 128 + n;
    const float* fl = f1 + h * 512;
    for (int k = 0; k < 512; k++) p += fl[k] * w2[(size_t)k * 128];
    part[t] = p;
    __syncthreads();
    if (t < 128) out[(size_t)g * 128 + t] = part[t] + part[t + 128] + bf2[t];
}

extern "C" void kernel_launch(void* const* d_in, const int* in_sizes, int n_in,
                              void* d_out, int out_size, void* d_ws, size_t ws_size,
                              hipStream_t stream) {
    const float* x    = (const float*)d_in[0];
    const int*   ei   = (const int*)d_in[1];
    const int*   batch= (const int*)d_in[2];
    const float* W1 = (const float*)d_in[3];  const float* b1  = (const float*)d_in[4];
    const float* W2 = (const float*)d_in[5];  const float* b2  = (const float*)d_in[6];
    const float* W3 = (const float*)d_in[7];  const float* b3  = (const float*)d_in[8];
    const float* Wf1= (const float*)d_in[9];  const float* bf1 = (const float*)d_in[10];
    const float* Wf2= (const float*)d_in[11]; const float* bf2 = (const float*)d_in[12];
    float* out = (float*)d_out;

    const int* srcp = ei;
    const int* dstp = ei + EDGES;

    char* p = (char*)d_ws;
    size_t o = 0;
    auto takeB = [&](size_t bytes) { char* q = p + o; o += (bytes + 255) & ~(size_t)255; return q; };
    int*   cnt      = (int*)takeB(NODES * 4);
    int*   cursor   = (int*)takeB(NODES * 4);
    int*   rowstart = (int*)takeB(NODES * 4);
    float* dinv     = (float*)takeB(NODES * 4);
    int*   csr_src  = (int*)takeB(EDGES * 4);
    unsigned short* aggH = (unsigned short*)takeB((size_t)MPAD * 160 * 2);
    unsigned short* aggL = (unsigned short*)takeB((size_t)MPAD * 160 * 2);
    float* xs     = (float*)takeB((size_t)NODES * 80 * 4);
    float* hbuf   = (float*)takeB((size_t)NODES * 312 * 4);
    float* pooled = (float*)takeB((size_t)GRAPHS * 312 * 4);
    unsigned short* Wt1h = (unsigned short*)takeB(128 * 96 * 2);
    unsigned short* Wt1l = (unsigned short*)takeB(128 * 96 * 2);
    unsigned short* Wt2h = (unsigned short*)takeB(192 * 96 * 2);
    unsigned short* Wt2l = (unsigned short*)takeB(192 * 96 * 2);
    unsigned short* Wt3h = (unsigned short*)takeB(320 * 160 * 2);
    unsigned short* Wt3l = (unsigned short*)takeB(320 * 160 * 2);
    (void)ws_size;

    hipMemsetAsync(cnt, 0, NODES * sizeof(int), stream);
    hipMemsetAsync(cursor, 0, NODES * sizeof(int), stream);

    wsplit_kernel<<<128, 96, 0, stream>>>(W1, Wt1h, Wt1l, 78, 78, 96);
    wsplit_kernel<<<192, 96, 0, stream>>>(W2, Wt2h, Wt2l, 78, 156, 96);
    wsplit_kernel<<<320, 160, 0, stream>>>(W3, Wt3h, Wt3l, 156, 312, 160);

    count_kernel<<<(EDGES + 255) / 256, 256, 0, stream>>>(dstp, cnt, EDGES);
    dinv_kernel<<<(NODES + 255) / 256, 256, 0, stream>>>(cnt, dinv, NODES);
    scan_kernel<<<1, 1024, 0, stream>>>(cnt, rowstart, NODES);
    fill_kernel<<<(EDGES + 255) / 256, 256, 0, stream>>>(srcp, dstp, rowstart, cursor, csr_src, EDGES);

    const int NBLK = MPAD / 64;   // 469
    const int AGRID = NODES / 4;  // 7500

    // layer 1: prescale (stride 80, zero pad) -> agg -> gemm (C stride 80, pad zeroed)
    prescale_kernel<<<(NODES * 80 + 255) / 256, 256, 0, stream>>>(x, dinv, xs, NODES * 80);
    agg_split_v3<20, 24><<<AGRID, 256, 0, stream>>>(xs, rowstart, cnt, csr_src, dinv, aggH, aggL);
    mfma_gemm_v2<3><<<NBLK, 256, 3 * 16384, stream>>>(aggH, aggL, Wt1h, Wt1l, b1, dinv, hbuf,
                                                      NODES, 78, 80, 2, 1);
    // layer 2 (input stride 80, output stride 160)
    agg_split_v3<20, 24><<<AGRID, 256, 0, stream>>>(hbuf, rowstart, cnt, csr_src, dinv, aggH, aggL);
    mfma_gemm_v2<3><<<NBLK, 256, 3 * 16384, stream>>>(aggH, aggL, Wt2h, Wt2l, b2, dinv, hbuf,
                                                      NODES, 156, 160, 3, 1);
    // layer 3 (input stride 160, output stride 312, unscaled for pooling)
    agg_split_v3<40, 40><<<AGRID, 256, 0, stream>>>(hbuf, rowstart, cnt, csr_src, dinv, aggH, aggL);
    mfma_gemm_v2<5><<<NBLK, 256, 5 * 16384, stream>>>(aggH, aggL, Wt3h, Wt3l, b3, nullptr, hbuf,
                                                      NODES, 312, 312, 5, 1);

    pool_kernel<<<GRAPHS, 128, 0, stream>>>(hbuf, batch, pooled, NODES, GRAPHS);
    fc_fused_kernel<<<GRAPHS, 256, 0, stream>>>(pooled, Wf1, bf1, Wf2, bf2, out);
}